// Round 11
// baseline (349.458 us; speedup 1.0000x reference)
//
#include <hip/hip_runtime.h>
#include <hip/hip_cooperative_groups.h>
#include <math.h>

namespace cg = cooperative_groups;

typedef _Float16 f16;
typedef _Float16 f16x8 __attribute__((ext_vector_type(8)));
typedef float f32x4 __attribute__((ext_vector_type(4)));

#define H2_STRIDE 136   // f16 per row = 272 B = 17x16 -> every row 16-B aligned.
// STRIDE ERRATA (r5/r7): 140 leaves odd rows 8-B aligned -> b128 splits -> +24us.
// OCCUPANCY ERRATA (r10): VGPR_Count=124 excludes AGPRs; true total ~190 ->
// 8 waves/CU hard cap -> 2-blocks/CU co-residency is IMPOSSIBLE with the
// 144-reg resident-fragment design.  Grid must stay 256 (1 block/batch).
// SCHEDULE: A-first then B (r9: B-first = 71->180us).  No s_setprio (r5).
// 1 barrier/chunk (r4: wider windows spill).  Fragments via f16x8 loads from
// pre-transposed W3t/W2t (r6: direct fp32+cvt spills ~110 regs).

// ---------------------------------------------------------------------------
// LDS layouts (phase-overlaid in the fused kernel via char[] union)
// ---------------------------------------------------------------------------
struct PnLds {
    __align__(16) f16 h2s[2][128 * H2_STRIDE];  // 68 KB
    float xs[3072];                              // 12 KB
    __align__(16) float wls[288];
    float b2s[128];
};
struct HdLds {
    float gsm[2][1024];
    float z1p[4][2][512];
    float z1s[2][512];
    float z2p[8][2][256];
    float z2s[2][256];
    float l3p[16][2][9];
    float wh3s[2304];
    float raw[2][12];
};

// ---------------------------------------------------------------------------
// Phase 0: weight prep (grid-strided).  W3t[c][k]=f16(W3[k][c]), W2t likewise,
// wpk[k][4] = {W1[0][k],W1[1][k],W1[2][k],b1[k]}.
// ---------------------------------------------------------------------------
__device__ void phase_prep(int idx, int stride,
    const float* __restrict__ W1, const float* __restrict__ b1,
    const float* __restrict__ W2, const float* __restrict__ W3,
    f16* __restrict__ W2t, f16* __restrict__ W3t, float* __restrict__ wpk)
{
    for (int i = idx; i < 1024 * 128; i += stride) {
        int c = i >> 7, k = i & 127;
        W3t[i] = (f16)W3[k * 1024 + c];
    }
    for (int i = idx; i < 128 * 64; i += stride) {
        int c = i >> 6, k = i & 63;
        W2t[i] = (f16)W2[k * 128 + c];
    }
    if (idx < 256) {
        int k = idx >> 2, c = idx & 3;
        wpk[idx] = (c < 3) ? W1[c * 64 + k] : b1[k];
    }
}

// ---------------------------------------------------------------------------
// Phase 1: PointNet layers 1-3 + max-pool for batch b (r8-exact, 71.4 us).
// 512 threads = 8 waves; one block per batch.
// ---------------------------------------------------------------------------
__device__ void phase_pointnet(PnLds& L, int b, int tid,
    const float* __restrict__ x, const float* __restrict__ wpk,
    const f16* __restrict__ W2t, const float* __restrict__ b2,
    const f16* __restrict__ W3t, const float* __restrict__ b3,
    float* __restrict__ g)
{
    int lane = tid & 63, w = tid >> 6;
    int lrow = lane & 15, quad = lane >> 4;
    int wr2 = w & 3, wc2 = w >> 2;

    // B fragments first: latency hides under staging
    f16x8 bf3[8][4];
    {
        const f16* base = W3t + (size_t)(w * 128 + lrow) * 128 + quad * 8;
#pragma unroll
        for (int ct = 0; ct < 8; ct++)
#pragma unroll
            for (int kc = 0; kc < 4; kc++)
                bf3[ct][kc] = *(const f16x8*)(base + ct * 16 * 128 + kc * 32);
    }
    f16x8 bf2[4][2];
    {
        const f16* base = W2t + (size_t)(wc2 * 64 + lrow) * 64 + quad * 8;
#pragma unroll
        for (int ct = 0; ct < 4; ct++)
#pragma unroll
            for (int kc2 = 0; kc2 < 2; kc2++)
                bf2[ct][kc2] = *(const f16x8*)(base + ct * 16 * 64 + kc2 * 32);
    }

    {
        const float* xb = x + (size_t)b * 3072;
        for (int i = tid; i < 3072; i += 512) L.xs[i] = xb[i];
        if (tid < 256) {
            int k = tid >> 2, c = tid & 3;
            L.wls[(k + (k >> 3)) * 4 + c] = wpk[tid];
        }
        if (tid >= 256 && tid < 384) L.b2s[tid - 256] = b2[tid - 256];
    }
    __syncthreads();

    const f32x4 z4 = {0.f, 0.f, 0.f, 0.f};
    float cmax[8];
#pragma unroll
    for (int ct = 0; ct < 8; ct++) cmax[ct] = -3.0e38f;

    auto phaseA = [&](int chunk) {
        f16* hb = L.h2s[chunk & 1];
        int p0 = chunk * 128 + wr2 * 32 + lrow;
        float x00 = L.xs[p0 * 3], x01 = L.xs[p0 * 3 + 1], x02 = L.xs[p0 * 3 + 2];
        int p1 = p0 + 16;
        float x10 = L.xs[p1 * 3], x11 = L.xs[p1 * 3 + 1], x12 = L.xs[p1 * 3 + 2];
        f32x4 acc2[2][4];
#pragma unroll
        for (int kc2 = 0; kc2 < 2; kc2++) {
            f16x8 af2[2];
#pragma unroll
            for (int j = 0; j < 8; j++) {
                int k = kc2 * 32 + quad * 8 + j;
                f32x4 wv = *(const f32x4*)&L.wls[(k + (k >> 3)) * 4];
                float v0 = fmaf(x02, wv[2], fmaf(x01, wv[1], fmaf(x00, wv[0], wv[3])));
                float v1 = fmaf(x12, wv[2], fmaf(x11, wv[1], fmaf(x10, wv[0], wv[3])));
                af2[0][j] = (f16)fmaxf(v0, 0.f);
                af2[1][j] = (f16)fmaxf(v1, 0.f);
            }
#pragma unroll
            for (int rt = 0; rt < 2; rt++)
#pragma unroll
                for (int ct = 0; ct < 4; ct++)
                    acc2[rt][ct] = __builtin_amdgcn_mfma_f32_16x16x32_f16(
                        af2[rt], bf2[ct][kc2], kc2 ? acc2[rt][ct] : z4, 0, 0, 0);
        }
#pragma unroll
        for (int rt = 0; rt < 2; rt++)
#pragma unroll
            for (int ct = 0; ct < 4; ct++) {
                int col = wc2 * 64 + ct * 16 + lrow;
                float bb = L.b2s[col];
                int rowb = wr2 * 32 + rt * 16 + quad * 4;
#pragma unroll
                for (int r = 0; r < 4; r++)
                    hb[(rowb + r) * H2_STRIDE + col] = (f16)fmaxf(acc2[rt][ct][r] + bb, 0.f);
            }
    };

    auto phaseB = [&](int chunk) {
        const f16* hb = L.h2s[chunk & 1];
#pragma unroll
        for (int rt = 0; rt < 8; rt++) {
            f32x4 acc[8];
#pragma unroll
            for (int kc = 0; kc < 4; kc++) {
                f16x8 af = *(const f16x8*)(hb + (rt * 16 + lrow) * H2_STRIDE + kc * 32 + quad * 8);
#pragma unroll
                for (int ct = 0; ct < 8; ct++)
                    acc[ct] = __builtin_amdgcn_mfma_f32_16x16x32_f16(
                        af, bf3[ct][kc], kc ? acc[ct] : z4, 0, 0, 0);
            }
#pragma unroll
            for (int ct = 0; ct < 8; ct++) {
                float m01 = fmaxf(acc[ct][0], acc[ct][1]);
                float m23 = fmaxf(acc[ct][2], acc[ct][3]);
                cmax[ct] = fmaxf(cmax[ct], fmaxf(m01, m23));
            }
        }
    };

    phaseA(0);
    __syncthreads();
#pragma unroll 1
    for (int c = 0; c < 7; c++) {
        phaseA(c + 1);
        phaseB(c);
        __syncthreads();
    }
    phaseB(7);

#pragma unroll
    for (int ct = 0; ct < 8; ct++) {
        cmax[ct] = fmaxf(cmax[ct], __shfl_xor(cmax[ct], 16, 64));
        cmax[ct] = fmaxf(cmax[ct], __shfl_xor(cmax[ct], 32, 64));
    }
    if (quad == 0) {
#pragma unroll
        for (int ct = 0; ct < 8; ct++) {
            int cg = w * 128 + ct * 16 + lrow;
            g[(size_t)b * 1024 + cg] = fmaxf(cmax[ct] + b3[cg], 0.f);
        }
    }
}

// ---------------------------------------------------------------------------
// SVD -> SO(3), fp64 Jacobi on M^T M (per-thread serial)
// ---------------------------------------------------------------------------
__device__ inline void jrot(double S[3][3], double V[3][3], int p, int q)
{
    double apq = S[p][q];
    if (fabs(apq) < 1e-36) return;
    double tau = (S[q][q] - S[p][p]) / (2.0 * apq);
    double t = (tau >= 0.0 ? 1.0 : -1.0) / (fabs(tau) + sqrt(1.0 + tau * tau));
    double c = 1.0 / sqrt(1.0 + t * t);
    double s = t * c;
    for (int k = 0; k < 3; k++) {
        double skp = S[k][p], skq = S[k][q];
        S[k][p] = c * skp - s * skq;  S[k][q] = s * skp + c * skq;
    }
    for (int k = 0; k < 3; k++) {
        double spk = S[p][k], sqk = S[q][k];
        S[p][k] = c * spk - s * sqk;  S[q][k] = s * spk + c * sqk;
    }
    for (int k = 0; k < 3; k++) {
        double vkp = V[k][p], vkq = V[k][q];
        V[k][p] = c * vkp - s * vkq;  V[k][q] = s * vkp + c * vkq;
    }
}

__device__ void svd_so3(const float* Mf, float* Rout)
{
    double M[3][3], S[3][3], V[3][3];
    for (int i = 0; i < 3; i++)
        for (int j = 0; j < 3; j++) M[i][j] = (double)Mf[3 * i + j];
    for (int i = 0; i < 3; i++)
        for (int j = 0; j < 3; j++)
            S[i][j] = M[0][i] * M[0][j] + M[1][i] * M[1][j] + M[2][i] * M[2][j];
    for (int i = 0; i < 3; i++)
        for (int j = 0; j < 3; j++) V[i][j] = (i == j) ? 1.0 : 0.0;
    for (int it = 0; it < 10; it++) {
        jrot(S, V, 0, 1); jrot(S, V, 0, 2); jrot(S, V, 1, 2);
    }
    double lam[3] = {S[0][0], S[1][1], S[2][2]};
    int i0 = 0, i1 = 1, i2 = 2, tt;
    if (lam[i0] < lam[i1]) { tt = i0; i0 = i1; i1 = tt; }
    if (lam[i0] < lam[i2]) { tt = i0; i0 = i2; i2 = tt; }
    if (lam[i1] < lam[i2]) { tt = i1; i1 = i2; i2 = tt; }
    double v0[3], v1[3], v2[3];
    for (int k = 0; k < 3; k++) { v0[k] = V[k][i0]; v1[k] = V[k][i1]; v2[k] = V[k][i2]; }
    double u1[3], u2[3], u3[3];
    for (int i = 0; i < 3; i++) u1[i] = M[i][0] * v0[0] + M[i][1] * v0[1] + M[i][2] * v0[2];
    double n1 = sqrt(u1[0] * u1[0] + u1[1] * u1[1] + u1[2] * u1[2]) + 1e-300;
    for (int i = 0; i < 3; i++) u1[i] /= n1;
    for (int i = 0; i < 3; i++) u2[i] = M[i][0] * v1[0] + M[i][1] * v1[1] + M[i][2] * v1[2];
    double d12 = u1[0] * u2[0] + u1[1] * u2[1] + u1[2] * u2[2];
    for (int i = 0; i < 3; i++) u2[i] -= d12 * u1[i];
    double n2 = sqrt(u2[0] * u2[0] + u2[1] * u2[1] + u2[2] * u2[2]) + 1e-300;
    for (int i = 0; i < 3; i++) u2[i] /= n2;
    u3[0] = u1[1] * u2[2] - u1[2] * u2[1];
    u3[1] = u1[2] * u2[0] - u1[0] * u2[2];
    u3[2] = u1[0] * u2[1] - u1[1] * u2[0];
    double c12x = v1[1] * v2[2] - v1[2] * v2[1];
    double c12y = v1[2] * v2[0] - v1[0] * v2[2];
    double c12z = v1[0] * v2[1] - v1[1] * v2[0];
    double detV = v0[0] * c12x + v0[1] * c12y + v0[2] * c12z;
    for (int i = 0; i < 3; i++)
        for (int j = 0; j < 3; j++)
            Rout[3 * i + j] = (float)(u1[i] * v0[j] + u2[i] * v1[j] + detV * u3[i] * v2[j]);
}

// ---------------------------------------------------------------------------
// Phase 2: head for batches {2*bb, 2*bb+1} (r8-exact head_batched body).
// ---------------------------------------------------------------------------
__device__ void phase_head(HdLds& L, int bb, int tid,
    const float* __restrict__ g,
    const float* __restrict__ Wh1, const float* __restrict__ bh1,
    const float* __restrict__ Wh2, const float* __restrict__ bh2,
    const float* __restrict__ Wh3, const float* __restrict__ bh3,
    float* __restrict__ out)
{
    int b0 = bb * 2;
    int roff = (bb * 131) & 255;   // de-phase L2 streams across CUs

    for (int i = tid; i < 2048; i += 512)
        L.gsm[i >> 10][i & 1023] = g[(size_t)(b0 + (i >> 10)) * 1024 + (i & 1023)];
    for (int i = tid; i < 2304; i += 512) L.wh3s[i] = Wh3[i];
    __syncthreads();

    // layer 1: 4-way k-split, rotated k-walk
    {
        int cg = tid & 127;
        int ks = tid >> 7;
        int k0 = ks * 256;
        f32x4 a0 = {0.f, 0.f, 0.f, 0.f}, a1 = {0.f, 0.f, 0.f, 0.f};
        const float* wp = Wh1 + cg * 4;
#pragma unroll 4
        for (int kk = 0; kk < 256; kk++) {
            int k = k0 + ((kk + roff) & 255);
            f32x4 wv = *(const f32x4*)(wp + (size_t)k * 512);
            float g0 = L.gsm[0][k], g1 = L.gsm[1][k];
            a0[0] = fmaf(g0, wv[0], a0[0]);  a1[0] = fmaf(g1, wv[0], a1[0]);
            a0[1] = fmaf(g0, wv[1], a0[1]);  a1[1] = fmaf(g1, wv[1], a1[1]);
            a0[2] = fmaf(g0, wv[2], a0[2]);  a1[2] = fmaf(g1, wv[2], a1[2]);
            a0[3] = fmaf(g0, wv[3], a0[3]);  a1[3] = fmaf(g1, wv[3], a1[3]);
        }
        *(f32x4*)&L.z1p[ks][0][cg * 4] = a0;
        *(f32x4*)&L.z1p[ks][1][cg * 4] = a1;
    }
    __syncthreads();
    for (int i = tid; i < 1024; i += 512) {
        int r = i >> 9, col = i & 511;
        float v = bh1[col] + L.z1p[0][r][col] + L.z1p[1][r][col]
                           + L.z1p[2][r][col] + L.z1p[3][r][col];
        L.z1s[r][col] = fmaxf(v, 0.f);
    }
    __syncthreads();

    // layer 2: 8-way k-split, rotated
    {
        int cg = tid & 63;
        int ks = tid >> 6;
        int k0 = ks * 64;
        int roff2 = roff & 63;
        f32x4 a0 = {0.f, 0.f, 0.f, 0.f}, a1 = {0.f, 0.f, 0.f, 0.f};
        const float* wp = Wh2 + cg * 4;
#pragma unroll 4
        for (int kk = 0; kk < 64; kk++) {
            int k = k0 + ((kk + roff2) & 63);
            f32x4 wv = *(const f32x4*)(wp + (size_t)k * 256);
            float z0 = L.z1s[0][k], z1v = L.z1s[1][k];
            a0[0] = fmaf(z0, wv[0], a0[0]);  a1[0] = fmaf(z1v, wv[0], a1[0]);
            a0[1] = fmaf(z0, wv[1], a0[1]);  a1[1] = fmaf(z1v, wv[1], a1[1]);
            a0[2] = fmaf(z0, wv[2], a0[2]);  a1[2] = fmaf(z1v, wv[2], a1[2]);
            a0[3] = fmaf(z0, wv[3], a0[3]);  a1[3] = fmaf(z1v, wv[3], a1[3]);
        }
        *(f32x4*)&L.z2p[ks][0][cg * 4] = a0;
        *(f32x4*)&L.z2p[ks][1][cg * 4] = a1;
    }
    __syncthreads();
    {
        int r = tid >> 8, col = tid & 255;
        float v = bh2[col];
#pragma unroll
        for (int j = 0; j < 8; j++) v += L.z2p[j][r][col];
        L.z2s[r][col] = fmaxf(v, 0.f);
    }
    __syncthreads();

    // layer 3
    if (tid < 288) {
        int r = tid / 144, rem = tid - r * 144;
        int c = rem % 9, ks = rem / 9;
        float a = 0.f;
#pragma unroll
        for (int k = 0; k < 16; k++)
            a = fmaf(L.z2s[r][ks * 16 + k], L.wh3s[(ks * 16 + k) * 9 + c], a);
        L.l3p[ks][r][c] = a;
    }
    __syncthreads();
    if (tid < 18) {
        int r = tid / 9, c = tid - r * 9;
        float a = bh3[c];
#pragma unroll
        for (int j = 0; j < 16; j++) a += L.l3p[j][r][c];
        L.raw[r][c] = a;
    }
    __syncthreads();

    if (tid < 2)
        svd_so3(&L.raw[tid][0], out + (size_t)(b0 + tid) * 9);
}

// ---------------------------------------------------------------------------
// Fused cooperative kernel: prep -> grid.sync -> pointnet -> grid.sync -> head.
// Grid 256 x 512; 1 block/CU guaranteed (84 KB LDS) -> cooperative-residency OK.
// Saves 2 launch gaps + the prep kernel launch vs the r8 3-kernel chain.
// ---------------------------------------------------------------------------
__global__ __launch_bounds__(512, 2) void meganet(
    const float* __restrict__ x,
    const float* __restrict__ W1, const float* __restrict__ b1,
    const float* __restrict__ W2, const float* __restrict__ b2,
    const float* __restrict__ W3, const float* __restrict__ b3,
    const float* __restrict__ Wh1, const float* __restrict__ bh1,
    const float* __restrict__ Wh2, const float* __restrict__ bh2,
    const float* __restrict__ Wh3, const float* __restrict__ bh3,
    f16* __restrict__ W2t, f16* __restrict__ W3t, float* __restrict__ wpk,
    float* __restrict__ g, float* __restrict__ out)
{
    __shared__ __align__(16) char smem[sizeof(PnLds) > sizeof(HdLds) ? sizeof(PnLds) : sizeof(HdLds)];
    cg::grid_group grid = cg::this_grid();

    int tid = threadIdx.x;
    int bid = blockIdx.x;

    // phase 0: prep (grid-strided; 131072 threads = exactly 1 W3t elem each)
    phase_prep(bid * 512 + tid, 256 * 512, W1, b1, W2, W3, W2t, W3t, wpk);

    __threadfence();
    grid.sync();

    // phase 1: pointnet, one batch per block
    phase_pointnet(*reinterpret_cast<PnLds*>(smem), bid, tid, x, wpk, W2t, b2, W3t, b3, g);

    __threadfence();
    grid.sync();

    // phase 2: head, 2 batches per block on blocks 0..127
    if (bid < 128)
        phase_head(*reinterpret_cast<HdLds*>(smem), bid, tid, g,
                   Wh1, bh1, Wh2, bh2, Wh3, bh3, out);
}

// ---------------------------------------------------------------------------
// Fallback wrappers (exact r8 3-kernel chain) — used if cooperative launch
// is unavailable; guarantees we never do worse than r8's measured 172.5 us.
// ---------------------------------------------------------------------------
__global__ __launch_bounds__(256) void prep_k(
    const float* __restrict__ W1, const float* __restrict__ b1,
    const float* __restrict__ W2, const float* __restrict__ W3,
    f16* __restrict__ W2t, f16* __restrict__ W3t, float* __restrict__ wpk)
{
    phase_prep(blockIdx.x * 256 + threadIdx.x, gridDim.x * 256,
               W1, b1, W2, W3, W2t, W3t, wpk);
}

__global__ __launch_bounds__(512, 2) void pointnet_k(
    const float* __restrict__ x, const float* __restrict__ wpk,
    const f16* __restrict__ W2t, const float* __restrict__ b2,
    const f16* __restrict__ W3t, const float* __restrict__ b3,
    float* __restrict__ g)
{
    __shared__ PnLds L;
    phase_pointnet(L, blockIdx.x, threadIdx.x, x, wpk, W2t, b2, W3t, b3, g);
}

__global__ __launch_bounds__(512) void head_k(
    const float* __restrict__ g,
    const float* __restrict__ Wh1, const float* __restrict__ bh1,
    const float* __restrict__ Wh2, const float* __restrict__ bh2,
    const float* __restrict__ Wh3, const float* __restrict__ bh3,
    float* __restrict__ out)
{
    __shared__ HdLds L;
    phase_head(L, blockIdx.x, threadIdx.x, g, Wh1, bh1, Wh2, bh2, Wh3, bh3, out);
}

// ---------------------------------------------------------------------------
extern "C" void kernel_launch(void* const* d_in, const int* in_sizes, int n_in,
                              void* d_out, int out_size, void* d_ws, size_t ws_size,
                              hipStream_t stream)
{
    const float* x   = (const float*)d_in[0];
    const float* W1  = (const float*)d_in[1];
    const float* b1  = (const float*)d_in[2];
    const float* W2  = (const float*)d_in[3];
    const float* b2  = (const float*)d_in[4];
    const float* W3  = (const float*)d_in[5];
    const float* b3  = (const float*)d_in[6];
    const float* Wh1 = (const float*)d_in[7];
    const float* bh1 = (const float*)d_in[8];
    const float* Wh2 = (const float*)d_in[9];
    const float* bh2 = (const float*)d_in[10];
    const float* Wh3 = (const float*)d_in[11];
    const float* bh3 = (const float*)d_in[12];
    float* out = (float*)d_out;

    char* ws = (char*)d_ws;
    f16*   W2t = (f16*)ws;                  // 16 KB
    f16*   W3t = (f16*)(ws + 65536);        // 256 KB
    float* wpk = (float*)(ws + 524288);     // 1 KB
    float* g   = (float*)(ws + 1048576);    // 1 MB

    void* args[] = {
        (void*)&x, (void*)&W1, (void*)&b1, (void*)&W2, (void*)&b2,
        (void*)&W3, (void*)&b3, (void*)&Wh1, (void*)&bh1, (void*)&Wh2,
        (void*)&bh2, (void*)&Wh3, (void*)&bh3,
        (void*)&W2t, (void*)&W3t, (void*)&wpk, (void*)&g, (void*)&out
    };
    hipError_t err = hipLaunchCooperativeKernel(
        (const void*)meganet, dim3(256), dim3(512), args, 0, stream);

    if (err != hipSuccess) {
        // r8 fallback chain (measured 172.5 us total)
        prep_k<<<128, 256, 0, stream>>>(W1, b1, W2, W3, W2t, W3t, wpk);
        pointnet_k<<<256, 512, 0, stream>>>(x, wpk, W2t, b2, W3t, b3, g);
        head_k<<<128, 512, 0, stream>>>(g, Wh1, bh1, Wh2, bh2, Wh3, bh3, out);
    }
}

// Round 12
// 172.632 us; speedup vs baseline: 2.0243x; 2.0243x over previous
//
#include <hip/hip_runtime.h>
#include <math.h>

typedef _Float16 f16;
typedef _Float16 f16x8 __attribute__((ext_vector_type(8)));
typedef float f32x4 __attribute__((ext_vector_type(4)));

#define H2_STRIDE 136   // f16 per row = 272 B = 17x16 -> every row 16-B aligned.
// STRIDE ERRATA (r5/r7): 140 leaves odd rows 8-B aligned -> b128 splits -> +24us
// (validated twice).  136 + ~2.1M write-conflict cycles (hidden under MFMA)
// is the measured optimum.  DO NOT CHANGE.
// STRUCTURE ERRATA (r3/r6/r11): every kernel-fusion attempt (serial-K head,
// low-MLP head, cooperative meganet) lost more to spill/parallelism-collapse
// than launch overhead costs.  The 3-kernel chain IS the right structure.
// OCCUPANCY ERRATA (r10): VGPR_Count excludes AGPRs; true per-wave total ~190
// -> 8 waves/CU hard cap; 2-blocks/CU is impossible with resident fragments.

// ---------------------------------------------------------------------------
// Prep: W3t[c][k] = f16(W3[k][c])  (1024x128), W2t[c][k] = f16(W2[k][c])
// (128x64), wpk[k][4] = {W1[0][k], W1[1][k], W1[2][k], b1[k]} fp32.
// LOAD-BEARING (r6/r9): fragments must be f16x8 vector loads from these
// transposed buffers.  Direct fp32+cvt in the main kernel spills (~110 regs).
// ---------------------------------------------------------------------------
__global__ __launch_bounds__(256) void prep_weights(
    const float* __restrict__ W1, const float* __restrict__ b1,
    const float* __restrict__ W2, const float* __restrict__ W3,
    f16* __restrict__ W2t, f16* __restrict__ W3t, float* __restrict__ wpk)
{
    int idx = blockIdx.x * 256 + threadIdx.x;
    int stride = gridDim.x * 256;
    for (int i = idx; i < 1024 * 128; i += stride) {
        int c = i >> 7, k = i & 127;
        W3t[i] = (f16)W3[k * 1024 + c];
    }
    for (int i = idx; i < 128 * 64; i += stride) {
        int c = i >> 6, k = i & 63;
        W2t[i] = (f16)W2[k * 128 + c];
    }
    if (idx < 256) {
        int k = idx >> 2, c = idx & 3;
        wpk[idx] = (c < 3) ? W1[c * 64 + k] : b1[k];
    }
}

// ---------------------------------------------------------------------------
// Fused PointNet: layers 1-3 + max-pool, one block per batch (grid = 256 =
// 1 block/CU).  512 threads = 8 waves.  EXACT r8-measured structure (71.4 us).
// REGISTER DISCIPLINE: bf3+bf2 = 144 VGPRs resident =>
//  (a) __launch_bounds__(512, 2) required (r2: min-waves=4 -> full spill);
//  (b) 1 barrier per chunk (r4: wider windows spill ~90 regs);
//  (c) fragments via f16x8 loads from W3t/W2t (r6/r9);
//  (d) phaseA BEFORE phaseB in the window (r9: B-first = 71->180 us);
//  (e) NO s_setprio (r5).
// ---------------------------------------------------------------------------
__global__ __launch_bounds__(512, 2) void pointnet_fused(
    const float* __restrict__ x,   // [B][1024][3]
    const float* __restrict__ wpk, // [64][4] {w0,w1,w2,b1}
    const f16* __restrict__ W2t,   // [128 c][64 k]
    const float* __restrict__ b2,  // [128]
    const f16* __restrict__ W3t,   // [1024 c][128 k]
    const float* __restrict__ b3,  // [1024]
    float* __restrict__ g)         // [B][1024]
{
    __shared__ float xs[1024 * 3];                        // 12 KB, whole batch
    __shared__ __align__(16) float wls[288];              // staggered W1+b1 pack
    __shared__ float b2s[128];
    __shared__ __align__(16) f16 h2s[2][128 * H2_STRIDE]; // 2 x 34 KB

    int b = blockIdx.x;
    int tid = threadIdx.x;
    int lane = tid & 63, w = tid >> 6;        // wave id 0..7
    int lrow = lane & 15, quad = lane >> 4;
    int wr2 = w & 3, wc2 = w >> 2;            // layer2 role: 32-row, 64-col tile

    // ---- B fragments issued first: latency hides under staging -------------
    f16x8 bf3[8][4];  // layer3, wave strip = cols [w*128, w*128+128)
    {
        const f16* base = W3t + (size_t)(w * 128 + lrow) * 128 + quad * 8;
#pragma unroll
        for (int ct = 0; ct < 8; ct++)
#pragma unroll
            for (int kc = 0; kc < 4; kc++)
                bf3[ct][kc] = *(const f16x8*)(base + ct * 16 * 128 + kc * 32);
    }
    f16x8 bf2[4][2];  // layer2
    {
        const f16* base = W2t + (size_t)(wc2 * 64 + lrow) * 64 + quad * 8;
#pragma unroll
        for (int ct = 0; ct < 4; ct++)
#pragma unroll
            for (int kc2 = 0; kc2 < 2; kc2++)
                bf2[ct][kc2] = *(const f16x8*)(base + ct * 16 * 64 + kc2 * 32);
    }

    // ---- stage x (whole batch), layer1 weights (staggered), b2 -------------
    {
        const float* xb = x + (size_t)b * 3072;
        for (int i = tid; i < 3072; i += 512) xs[i] = xb[i];
        if (tid < 256) {
            int k = tid >> 2, c = tid & 3;
            wls[(k + (k >> 3)) * 4 + c] = wpk[tid];
        }
        if (tid >= 256 && tid < 384) b2s[tid - 256] = b2[tid - 256];
    }
    __syncthreads();

    const f32x4 z4 = {0.f, 0.f, 0.f, 0.f};
    float cmax[8];
#pragma unroll
    for (int ct = 0; ct < 8; ct++) cmax[ct] = -3.0e38f;

    // phase A: layers 1+2 for `chunk` -> h2s[chunk&1]
    auto phaseA = [&](int chunk) {
        f16* hb = h2s[chunk & 1];
        int p0 = chunk * 128 + wr2 * 32 + lrow;
        float x00 = xs[p0 * 3], x01 = xs[p0 * 3 + 1], x02 = xs[p0 * 3 + 2];
        int p1 = p0 + 16;
        float x10 = xs[p1 * 3], x11 = xs[p1 * 3 + 1], x12 = xs[p1 * 3 + 2];
        f32x4 acc2[2][4];
#pragma unroll
        for (int kc2 = 0; kc2 < 2; kc2++) {
            f16x8 af2[2];
#pragma unroll
            for (int j = 0; j < 8; j++) {
                int k = kc2 * 32 + quad * 8 + j;
                f32x4 wv = *(const f32x4*)&wls[(k + (k >> 3)) * 4];
                float v0 = fmaf(x02, wv[2], fmaf(x01, wv[1], fmaf(x00, wv[0], wv[3])));
                float v1 = fmaf(x12, wv[2], fmaf(x11, wv[1], fmaf(x10, wv[0], wv[3])));
                af2[0][j] = (f16)fmaxf(v0, 0.f);
                af2[1][j] = (f16)fmaxf(v1, 0.f);
            }
#pragma unroll
            for (int rt = 0; rt < 2; rt++)
#pragma unroll
                for (int ct = 0; ct < 4; ct++)
                    acc2[rt][ct] = __builtin_amdgcn_mfma_f32_16x16x32_f16(
                        af2[rt], bf2[ct][kc2], kc2 ? acc2[rt][ct] : z4, 0, 0, 0);
        }
        // bias + relu + cvt -> LDS tile
#pragma unroll
        for (int rt = 0; rt < 2; rt++)
#pragma unroll
            for (int ct = 0; ct < 4; ct++) {
                int col = wc2 * 64 + ct * 16 + lrow;
                float bb = b2s[col];
                int rowb = wr2 * 32 + rt * 16 + quad * 4;
#pragma unroll
                for (int r = 0; r < 4; r++)
                    hb[(rowb + r) * H2_STRIDE + col] = (f16)fmaxf(acc2[rt][ct][r] + bb, 0.f);
            }
    };

    // phase B: layer3 MFMA from h2s[chunk&1], running col-max
    auto phaseB = [&](int chunk) {
        const f16* hb = h2s[chunk & 1];
#pragma unroll
        for (int rt = 0; rt < 8; rt++) {
            f32x4 acc[8];
#pragma unroll
            for (int kc = 0; kc < 4; kc++) {
                f16x8 af = *(const f16x8*)(hb + (rt * 16 + lrow) * H2_STRIDE + kc * 32 + quad * 8);
#pragma unroll
                for (int ct = 0; ct < 8; ct++)
                    acc[ct] = __builtin_amdgcn_mfma_f32_16x16x32_f16(
                        af, bf3[ct][kc], kc ? acc[ct] : z4, 0, 0, 0);
            }
#pragma unroll
            for (int ct = 0; ct < 8; ct++) {
                float m01 = fmaxf(acc[ct][0], acc[ct][1]);
                float m23 = fmaxf(acc[ct][2], acc[ct][3]);
                cmax[ct] = fmaxf(cmax[ct], fmaxf(m01, m23));
            }
        }
    };

    phaseA(0);
    __syncthreads();
#pragma unroll 1
    for (int c = 0; c < 7; c++) {
        phaseA(c + 1);   // fills other buffer; compiler interleaves with phaseB(c)
        phaseB(c);
        __syncthreads();
    }
    phaseB(7);

    // cross-quad reduce (quads hold disjoint row subsets of same col)
#pragma unroll
    for (int ct = 0; ct < 8; ct++) {
        cmax[ct] = fmaxf(cmax[ct], __shfl_xor(cmax[ct], 16, 64));
        cmax[ct] = fmaxf(cmax[ct], __shfl_xor(cmax[ct], 32, 64));
    }
    if (quad == 0) {
#pragma unroll
        for (int ct = 0; ct < 8; ct++) {
            int cg = w * 128 + ct * 16 + lrow;
            g[(size_t)b * 1024 + cg] = fmaxf(cmax[ct] + b3[cg], 0.f);
        }
    }
}

// ---------------------------------------------------------------------------
// SVD -> SO(3) projection, fp64 Jacobi on M^T M (per-thread serial)
// ---------------------------------------------------------------------------
__device__ inline void jrot(double S[3][3], double V[3][3], int p, int q)
{
    double apq = S[p][q];
    if (fabs(apq) < 1e-36) return;
    double tau = (S[q][q] - S[p][p]) / (2.0 * apq);
    double t = (tau >= 0.0 ? 1.0 : -1.0) / (fabs(tau) + sqrt(1.0 + tau * tau));
    double c = 1.0 / sqrt(1.0 + t * t);
    double s = t * c;
    for (int k = 0; k < 3; k++) {
        double skp = S[k][p], skq = S[k][q];
        S[k][p] = c * skp - s * skq;  S[k][q] = s * skp + c * skq;
    }
    for (int k = 0; k < 3; k++) {
        double spk = S[p][k], sqk = S[q][k];
        S[p][k] = c * spk - s * sqk;  S[q][k] = s * spk + c * sqk;
    }
    for (int k = 0; k < 3; k++) {
        double vkp = V[k][p], vkq = V[k][q];
        V[k][p] = c * vkp - s * vkq;  V[k][q] = s * vkp + c * vkq;
    }
}

__device__ void svd_so3(const float* Mf, float* Rout)
{
    double M[3][3], S[3][3], V[3][3];
    for (int i = 0; i < 3; i++)
        for (int j = 0; j < 3; j++) M[i][j] = (double)Mf[3 * i + j];
    for (int i = 0; i < 3; i++)
        for (int j = 0; j < 3; j++)
            S[i][j] = M[0][i] * M[0][j] + M[1][i] * M[1][j] + M[2][i] * M[2][j];
    for (int i = 0; i < 3; i++)
        for (int j = 0; j < 3; j++) V[i][j] = (i == j) ? 1.0 : 0.0;
    for (int it = 0; it < 10; it++) {
        jrot(S, V, 0, 1); jrot(S, V, 0, 2); jrot(S, V, 1, 2);
    }
    double lam[3] = {S[0][0], S[1][1], S[2][2]};
    int i0 = 0, i1 = 1, i2 = 2, tt;
    if (lam[i0] < lam[i1]) { tt = i0; i0 = i1; i1 = tt; }
    if (lam[i0] < lam[i2]) { tt = i0; i0 = i2; i2 = tt; }
    if (lam[i1] < lam[i2]) { tt = i1; i1 = i2; i2 = tt; }
    double v0[3], v1[3], v2[3];
    for (int k = 0; k < 3; k++) { v0[k] = V[k][i0]; v1[k] = V[k][i1]; v2[k] = V[k][i2]; }
    double u1[3], u2[3], u3[3];
    for (int i = 0; i < 3; i++) u1[i] = M[i][0] * v0[0] + M[i][1] * v0[1] + M[i][2] * v0[2];
    double n1 = sqrt(u1[0] * u1[0] + u1[1] * u1[1] + u1[2] * u1[2]) + 1e-300;
    for (int i = 0; i < 3; i++) u1[i] /= n1;
    for (int i = 0; i < 3; i++) u2[i] = M[i][0] * v1[0] + M[i][1] * v1[1] + M[i][2] * v1[2];
    double d12 = u1[0] * u2[0] + u1[1] * u2[1] + u1[2] * u2[2];
    for (int i = 0; i < 3; i++) u2[i] -= d12 * u1[i];
    double n2 = sqrt(u2[0] * u2[0] + u2[1] * u2[1] + u2[2] * u2[2]) + 1e-300;
    for (int i = 0; i < 3; i++) u2[i] /= n2;
    u3[0] = u1[1] * u2[2] - u1[2] * u2[1];
    u3[1] = u1[2] * u2[0] - u1[0] * u2[2];
    u3[2] = u1[0] * u2[1] - u1[1] * u2[0];
    double c12x = v1[1] * v2[2] - v1[2] * v2[1];
    double c12y = v1[2] * v2[0] - v1[0] * v2[2];
    double c12z = v1[0] * v2[1] - v1[1] * v2[0];
    double detV = v0[0] * c12x + v0[1] * c12y + v0[2] * c12z;
    for (int i = 0; i < 3; i++)
        for (int j = 0; j < 3; j++)
            Rout[3 * i + j] = (float)(u1[i] * v0[j] + u2[i] * v1[j] + detV * u3[i] * v2[j]);
}

// ---------------------------------------------------------------------------
// Head, one kernel: 128 blocks x 2 batches, 512 threads, k-split per layer
// (r8-measured config).  r12 tweak: the rotated k-walk is expressed as TWO
// LINEAR segments (same accumulation order -> bit-identical) so the compiler
// uses incremented addressing and unroll 8 -> more weight loads in flight in
// this L2-latency-bound stream.
// ---------------------------------------------------------------------------
__global__ __launch_bounds__(512) void head_batched(
    const float* __restrict__ g,   // [256][1024] (bias+relu applied)
    const float* __restrict__ Wh1, const float* __restrict__ bh1,
    const float* __restrict__ Wh2, const float* __restrict__ bh2,
    const float* __restrict__ Wh3, const float* __restrict__ bh3,
    float* __restrict__ out)
{
    __shared__ float gsm[2][1024];      // 8 KB
    __shared__ float z1p[4][2][512];    // 16 KB partials
    __shared__ float z1s[2][512];       // 4 KB
    __shared__ float z2p[8][2][256];    // 16 KB partials
    __shared__ float z2s[2][256];       // 2 KB
    __shared__ float l3p[16][2][9];
    __shared__ float wh3s[2304];        // 9 KB
    __shared__ float raw[2][12];

    int b0 = blockIdx.x * 2;
    int tid = threadIdx.x;
    int roff = (blockIdx.x * 131) & 255;   // de-phase L2 streams across CUs

    for (int i = tid; i < 2048; i += 512)
        gsm[i >> 10][i & 1023] = g[(size_t)(b0 + (i >> 10)) * 1024 + (i & 1023)];
    for (int i = tid; i < 2304; i += 512) wh3s[i] = Wh3[i];
    __syncthreads();

    // ---- layer 1: z1[2][512], 4-way k-split, rotated walk as 2 linear runs --
    {
        int cg = tid & 127;        // cols 4cg..4cg+3
        int ks = tid >> 7;         // k-slice 0..3, K=256 each
        int k0 = ks * 256;
        f32x4 a0 = {0.f, 0.f, 0.f, 0.f}, a1 = {0.f, 0.f, 0.f, 0.f};
        const float* wp = Wh1 + cg * 4;
        auto fma1 = [&](int k) {
            f32x4 wv = *(const f32x4*)(wp + (size_t)k * 512);
            float g0 = gsm[0][k], g1 = gsm[1][k];   // LDS broadcast
            a0[0] = fmaf(g0, wv[0], a0[0]);  a1[0] = fmaf(g1, wv[0], a1[0]);
            a0[1] = fmaf(g0, wv[1], a0[1]);  a1[1] = fmaf(g1, wv[1], a1[1]);
            a0[2] = fmaf(g0, wv[2], a0[2]);  a1[2] = fmaf(g1, wv[2], a1[2]);
            a0[3] = fmaf(g0, wv[3], a0[3]);  a1[3] = fmaf(g1, wv[3], a1[3]);
        };
#pragma unroll 8
        for (int k = k0 + roff; k < k0 + 256; k++) fma1(k);
#pragma unroll 8
        for (int k = k0; k < k0 + roff; k++) fma1(k);
        *(f32x4*)&z1p[ks][0][cg * 4] = a0;
        *(f32x4*)&z1p[ks][1][cg * 4] = a1;
    }
    __syncthreads();
    for (int i = tid; i < 1024; i += 512) {
        int r = i >> 9, col = i & 511;
        float v = bh1[col] + z1p[0][r][col] + z1p[1][r][col]
                           + z1p[2][r][col] + z1p[3][r][col];
        z1s[r][col] = fmaxf(v, 0.f);
    }
    __syncthreads();

    // ---- layer 2: z2[2][256], 8-way k-split, rotated walk as 2 linear runs --
    {
        int cg = tid & 63;         // cols 4cg..4cg+3
        int ks = tid >> 6;         // k-slice 0..7, K=64 each
        int k0 = ks * 64;
        int roff2 = roff & 63;
        f32x4 a0 = {0.f, 0.f, 0.f, 0.f}, a1 = {0.f, 0.f, 0.f, 0.f};
        const float* wp = Wh2 + cg * 4;
        auto fma2 = [&](int k) {
            f32x4 wv = *(const f32x4*)(wp + (size_t)k * 256);
            float z0 = z1s[0][k], z1v = z1s[1][k];
            a0[0] = fmaf(z0, wv[0], a0[0]);  a1[0] = fmaf(z1v, wv[0], a1[0]);
            a0[1] = fmaf(z0, wv[1], a0[1]);  a1[1] = fmaf(z1v, wv[1], a1[1]);
            a0[2] = fmaf(z0, wv[2], a0[2]);  a1[2] = fmaf(z1v, wv[2], a1[2]);
            a0[3] = fmaf(z0, wv[3], a0[3]);  a1[3] = fmaf(z1v, wv[3], a1[3]);
        };
#pragma unroll 8
        for (int k = k0 + roff2; k < k0 + 64; k++) fma2(k);
#pragma unroll 8
        for (int k = k0; k < k0 + roff2; k++) fma2(k);
        *(f32x4*)&z2p[ks][0][cg * 4] = a0;
        *(f32x4*)&z2p[ks][1][cg * 4] = a1;
    }
    __syncthreads();
    {
        int r = tid >> 8, col = tid & 255;   // 512 threads = 2 x 256 exactly
        float v = bh2[col];
#pragma unroll
        for (int j = 0; j < 8; j++) v += z2p[j][r][col];
        z2s[r][col] = fmaxf(v, 0.f);
    }
    __syncthreads();

    // ---- layer 3: 2 batches x 9 cols x 16 k-slices --------------------------
    if (tid < 288) {
        int r = tid / 144, rem = tid - r * 144;
        int c = rem % 9, ks = rem / 9;     // K=16 each
        float a = 0.f;
#pragma unroll
        for (int k = 0; k < 16; k++)
            a = fmaf(z2s[r][ks * 16 + k], wh3s[(ks * 16 + k) * 9 + c], a);
        l3p[ks][r][c] = a;
    }
    __syncthreads();
    if (tid < 18) {
        int r = tid / 9, c = tid - r * 9;
        float a = bh3[c];
#pragma unroll
        for (int j = 0; j < 16; j++) a += l3p[j][r][c];
        raw[r][c] = a;
    }
    __syncthreads();

    if (tid < 2)
        svd_so3(&raw[tid][0], out + (size_t)(b0 + tid) * 9);
}

// ---------------------------------------------------------------------------
extern "C" void kernel_launch(void* const* d_in, const int* in_sizes, int n_in,
                              void* d_out, int out_size, void* d_ws, size_t ws_size,
                              hipStream_t stream)
{
    const float* x   = (const float*)d_in[0];
    const float* W1  = (const float*)d_in[1];
    const float* b1  = (const float*)d_in[2];
    const float* W2  = (const float*)d_in[3];
    const float* b2  = (const float*)d_in[4];
    const float* W3  = (const float*)d_in[5];
    const float* b3  = (const float*)d_in[6];
    const float* Wh1 = (const float*)d_in[7];
    const float* bh1 = (const float*)d_in[8];
    const float* Wh2 = (const float*)d_in[9];
    const float* bh2 = (const float*)d_in[10];
    const float* Wh3 = (const float*)d_in[11];
    const float* bh3 = (const float*)d_in[12];
    float* out = (float*)d_out;

    char* ws = (char*)d_ws;
    f16*   W2t = (f16*)ws;                  // 16 KB
    f16*   W3t = (f16*)(ws + 65536);        // 256 KB
    float* wpk = (float*)(ws + 524288);     // 1 KB
    float* g   = (float*)(ws + 1048576);    // 1 MB

    prep_weights<<<128, 256, 0, stream>>>(W1, b1, W2, W3, W2t, W3t, wpk);
    pointnet_fused<<<256, 512, 0, stream>>>(x, wpk, W2t, b2, W3t, b3, g);
    head_batched<<<128, 512, 0, stream>>>(g, Wh1, bh1, Wh2, bh2, Wh3, bh3, out);
}